// Round 1
// baseline (1041.566 us; speedup 1.0000x reference)
//
#include <hip/hip_runtime.h>
#include <math.h>

// ---------------------------------------------------------------------------
// HomoGAT: h = tanh(x@Wfc); two GAT layers (project, edge softmax by dst,
// weighted segment sum, bias, ELU); mean over heads.
// Strategy: build CSR by dst once per launch (no atomics in heavy path),
// fp32 tiled SGEMM for projections, per-dst-node block for edge softmax+agg.
// ---------------------------------------------------------------------------

__device__ __forceinline__ float leaky02(float x) { return x > 0.f ? x : 0.2f * x; }

// ---------------- SGEMM: C[M,N] = A[M,K] @ B[K,N], optional tanh -----------
// 128x128 tile, 256 threads, 8x8 microtile, BK=16. N,K multiples of 128/16.
template<bool TANH>
__global__ __launch_bounds__(256) void sgemm_kernel(const float* __restrict__ A,
                                                    const float* __restrict__ B,
                                                    float* __restrict__ C,
                                                    int M, int N, int K) {
    __shared__ float As[16][128 + 4];
    __shared__ float Bs[16][128 + 4];
    const int tid = threadIdx.x;
    const int row0 = blockIdx.x * 128;
    const int col0 = blockIdx.y * 128;
    const int tx = tid & 15;        // 0..15 -> 8 cols each
    const int ty = tid >> 4;        // 0..15 -> 8 rows each

    const int a_r = tid >> 2;           // 0..63
    const int a_k = (tid & 3) * 4;      // 0,4,8,12
    const int b_k = tid >> 5;           // 0..7
    const int b_n = (tid & 31) * 4;     // 0..124

    float acc[8][8];
#pragma unroll
    for (int i = 0; i < 8; ++i)
#pragma unroll
        for (int j = 0; j < 8; ++j) acc[i][j] = 0.f;

    for (int k0 = 0; k0 < K; k0 += 16) {
        // stage A (128 x 16), transposed into As[k][m]
#pragma unroll
        for (int p = 0; p < 2; ++p) {
            int r = a_r + p * 64;
            int gr = row0 + r;
            float4 v = make_float4(0.f, 0.f, 0.f, 0.f);
            if (gr < M) v = *reinterpret_cast<const float4*>(&A[(size_t)gr * K + k0 + a_k]);
            As[a_k + 0][r] = v.x;
            As[a_k + 1][r] = v.y;
            As[a_k + 2][r] = v.z;
            As[a_k + 3][r] = v.w;
        }
        // stage B (16 x 128)
#pragma unroll
        for (int p = 0; p < 2; ++p) {
            int kk = b_k + p * 8;
            float4 v = *reinterpret_cast<const float4*>(&B[(size_t)(k0 + kk) * N + col0 + b_n]);
            *reinterpret_cast<float4*>(&Bs[kk][b_n]) = v;
        }
        __syncthreads();
#pragma unroll
        for (int kk = 0; kk < 16; ++kk) {
            float a8[8], b8[8];
            *reinterpret_cast<float4*>(&a8[0]) = *reinterpret_cast<const float4*>(&As[kk][ty * 8]);
            *reinterpret_cast<float4*>(&a8[4]) = *reinterpret_cast<const float4*>(&As[kk][ty * 8 + 4]);
            *reinterpret_cast<float4*>(&b8[0]) = *reinterpret_cast<const float4*>(&Bs[kk][tx * 8]);
            *reinterpret_cast<float4*>(&b8[4]) = *reinterpret_cast<const float4*>(&Bs[kk][tx * 8 + 4]);
#pragma unroll
            for (int i = 0; i < 8; ++i)
#pragma unroll
                for (int j = 0; j < 8; ++j) acc[i][j] = fmaf(a8[i], b8[j], acc[i][j]);
        }
        __syncthreads();
    }

#pragma unroll
    for (int i = 0; i < 8; ++i) {
        int gr = row0 + ty * 8 + i;
        if (gr < M) {
#pragma unroll
            for (int j = 0; j < 8; j += 4) {
                float4 v;
                v.x = acc[i][j + 0];
                v.y = acc[i][j + 1];
                v.z = acc[i][j + 2];
                v.w = acc[i][j + 3];
                if (TANH) { v.x = tanhf(v.x); v.y = tanhf(v.y); v.z = tanhf(v.z); v.w = tanhf(v.w); }
                *reinterpret_cast<float4*>(&C[(size_t)gr * N + col0 + tx * 8 + j]) = v;
            }
        }
    }
}

// ---------------- el/er: per-node attention logits -------------------------
// el[n,h] = sum_d feat[n,h*64+d]*al[h*64+d];  er likewise with ar.
__global__ __launch_bounds__(256) void eler_kernel(const float* __restrict__ feat,
                                                   const float* __restrict__ al,
                                                   const float* __restrict__ ar,
                                                   float* __restrict__ el,
                                                   float* __restrict__ er) {
    const int n = blockIdx.x;
    const int t = threadIdx.x;
    float f = feat[(size_t)n * 256 + t];
    float pl = f * al[t];
    float pr = f * ar[t];
#pragma unroll
    for (int d = 32; d; d >>= 1) {
        pl += __shfl_down(pl, d, 64);
        pr += __shfl_down(pr, d, 64);
    }
    if ((t & 63) == 0) {
        el[n * 4 + (t >> 6)] = pl;
        er[n * 4 + (t >> 6)] = pr;
    }
}

// ---------------- CSR build ------------------------------------------------
__global__ void count_deg_kernel(const int* __restrict__ dst, int* __restrict__ deg, int E) {
    int i = blockIdx.x * blockDim.x + threadIdx.x;
    if (i < E) atomicAdd(&deg[dst[i]], 1);
}

__global__ __launch_bounds__(256) void scan_kernel(const int* __restrict__ deg,
                                                   int* __restrict__ offs,
                                                   int* __restrict__ cursor, int n) {
    __shared__ int wsum[4];
    const int tid = threadIdx.x, lane = tid & 63, wv = tid >> 6;
    int carry = 0;
    for (int base = 0; base < n; base += 256) {
        int i = base + tid;
        int v = (i < n) ? deg[i] : 0;
        int incl = v;
#pragma unroll
        for (int d = 1; d < 64; d <<= 1) {
            int t = __shfl_up(incl, d, 64);
            if (lane >= d) incl += t;
        }
        if (lane == 63) wsum[wv] = incl;
        __syncthreads();
        int woff = 0;
#pragma unroll
        for (int w = 0; w < 4; ++w)
            if (w < wv) woff += wsum[w];
        int excl = carry + woff + incl - v;
        if (i < n) { offs[i] = excl; cursor[i] = excl; }
        int tot = wsum[0] + wsum[1] + wsum[2] + wsum[3];
        __syncthreads();
        carry += tot;
    }
    if (tid == 0) offs[n] = carry;
}

__global__ void fill_csr_kernel(const int* __restrict__ src, const int* __restrict__ dst,
                                int* __restrict__ cursor, int* __restrict__ srcs_sorted, int E) {
    int i = blockIdx.x * blockDim.x + threadIdx.x;
    if (i < E) {
        int d = dst[i];
        int pos = atomicAdd(&cursor[d], 1);
        srcs_sorted[pos] = src[i];
    }
}

// ---------------- GAT aggregation per dst node -----------------------------
// Block = 256 threads = one dst node. Pass 1: per-head online softmax stats
// over incoming edges. Pass 2: thread c owns channel c, accumulates
// a_e * feat[src_e][c]. Epilogue: bias + ELU (+ head-mean if FINAL).
template<bool FINAL>
__global__ __launch_bounds__(256) void gat_agg_kernel(const float* __restrict__ feat,
                                                      const float* __restrict__ el,
                                                      const float* __restrict__ er,
                                                      const int* __restrict__ srcs,
                                                      const int* __restrict__ offs,
                                                      const float* __restrict__ bias,
                                                      float* __restrict__ out) {
    const int n = blockIdx.x;
    const int tid = threadIdx.x;
    const int begin = offs[n];
    const int end = offs[n + 1];

    __shared__ float s_m[256], s_z[256];
    __shared__ float s_mf[4], s_rz[4];

    // pass 1: thread handles head (tid&3), edges strided by 64
    {
        const int hh = tid & 3;
        const float erh = er[n * 4 + hh];
        float m = -INFINITY, z = 0.f;
        for (int p = begin + (tid >> 2); p < end; p += 64) {
            int s = srcs[p];
            float sc = leaky02(el[s * 4 + hh] + erh);
            float nm = fmaxf(m, sc);
            z = z * __expf(m - nm) + __expf(sc - nm);
            m = nm;
        }
        s_m[tid] = m;
        s_z[tid] = z;
    }
    __syncthreads();
#pragma unroll
    for (int st = 128; st >= 4; st >>= 1) {
        if (tid < st) {
            float m1 = s_m[tid], z1 = s_z[tid];
            float m2 = s_m[tid + st], z2 = s_z[tid + st];
            float nm = fmaxf(m1, m2);
            float nz = 0.f;
            if (nm != -INFINITY) nz = z1 * __expf(m1 - nm) + z2 * __expf(m2 - nm);
            s_m[tid] = nm;
            s_z[tid] = nz;
        }
        __syncthreads();
    }
    if (tid < 4) {
        s_mf[tid] = s_m[tid];
        s_rz[tid] = s_z[tid] > 0.f ? 1.0f / s_z[tid] : 0.f;
    }
    __syncthreads();

    // pass 2: thread owns channel c
    const int c = tid;
    const int h = c >> 6;
    const float mh = s_mf[h];
    const float rz = s_rz[h];
    const float erh = er[n * 4 + h];
    float acc = 0.f;
    for (int p = begin; p < end; ++p) {
        int s = srcs[p];
        float sc = leaky02(el[s * 4 + h] + erh);
        float a = __expf(sc - mh) * rz;
        acc = fmaf(a, feat[(size_t)s * 256 + c], acc);
    }
    float v = acc + bias[c];
    v = v > 0.f ? v : expm1f(v);  // ELU (alpha=1)

    if (!FINAL) {
        out[(size_t)n * 256 + c] = v;
    } else {
        __shared__ float s_v[256];
        s_v[c] = v;
        __syncthreads();
        if (tid < 64)
            out[(size_t)n * 64 + tid] =
                0.25f * (s_v[tid] + s_v[tid + 64] + s_v[tid + 128] + s_v[tid + 192]);
    }
}

// ---------------------------------------------------------------------------
extern "C" void kernel_launch(void* const* d_in, const int* in_sizes, int n_in,
                              void* d_out, int out_size, void* d_ws, size_t ws_size,
                              hipStream_t stream) {
    const float* x_feat = (const float*)d_in[0];
    const float* W_fc   = (const float*)d_in[1];
    const float* W1     = (const float*)d_in[2];
    const float* al1    = (const float*)d_in[3];
    const float* ar1    = (const float*)d_in[4];
    const float* b1     = (const float*)d_in[5];
    const float* W2     = (const float*)d_in[6];
    const float* al2    = (const float*)d_in[7];
    const float* ar2    = (const float*)d_in[8];
    const float* b2     = (const float*)d_in[9];
    const int*   src    = (const int*)d_in[10];
    const int*   dst    = (const int*)d_in[11];
    float* out = (float*)d_out;

    const int N = in_sizes[0] / 128;   // 50000
    const int E = in_sizes[10];        // 800000

    // workspace carve-up
    char* ws = (char*)d_ws;
    size_t off = 0;
    auto alloc = [&](size_t bytes) -> void* {
        off = (off + 255) & ~(size_t)255;
        void* p = ws + off;
        off += bytes;
        return p;
    };
    float* buf0 = (float*)alloc((size_t)N * 256 * 4);  // h, later g1
    float* buf1 = (float*)alloc((size_t)N * 256 * 4);  // feat1, later feat2
    float* el   = (float*)alloc((size_t)N * 4 * 4);
    float* er   = (float*)alloc((size_t)N * 4 * 4);
    int* deg    = (int*)alloc((size_t)N * 4);
    int* offs   = (int*)alloc((size_t)(N + 1) * 4);
    int* cursor = (int*)alloc((size_t)N * 4);
    int* srcs_sorted = (int*)alloc((size_t)E * 4);

    const int eb = (E + 255) / 256;
    dim3 ggrid((N + 127) / 128, 2);

    // CSR build (by dst)
    hipMemsetAsync(deg, 0, (size_t)N * 4, stream);
    count_deg_kernel<<<eb, 256, 0, stream>>>(dst, deg, E);
    scan_kernel<<<1, 256, 0, stream>>>(deg, offs, cursor, N);
    fill_csr_kernel<<<eb, 256, 0, stream>>>(src, dst, cursor, srcs_sorted, E);

    // h = tanh(x @ W_fc)
    sgemm_kernel<true><<<ggrid, 256, 0, stream>>>(x_feat, W_fc, buf0, N, 256, 128);
    // feat1 = h @ W1
    sgemm_kernel<false><<<ggrid, 256, 0, stream>>>(buf0, W1, buf1, N, 256, 256);
    eler_kernel<<<N, 256, 0, stream>>>(buf1, al1, ar1, el, er);
    // g1 (into buf0)
    gat_agg_kernel<false><<<N, 256, 0, stream>>>(buf1, el, er, srcs_sorted, offs, b1, buf0);
    // feat2 = g1 @ W2 (into buf1)
    sgemm_kernel<false><<<ggrid, 256, 0, stream>>>(buf0, W2, buf1, N, 256, 256);
    eler_kernel<<<N, 256, 0, stream>>>(buf1, al2, ar2, el, er);
    // final aggregation + head mean -> out
    gat_agg_kernel<true><<<N, 256, 0, stream>>>(buf1, el, er, srcs_sorted, offs, b2, out);
}

// Round 3
// 579.665 us; speedup vs baseline: 1.7968x; 1.7968x over previous
//
#include <hip/hip_runtime.h>
#include <hip/hip_bf16.h>
#include <math.h>

// ---------------------------------------------------------------------------
// HomoGAT on MI355X.
//  - GEMMs: split-precision bf16 MFMA (A=Ah+Al, B=Bh+Bl, 3 products, fp32 acc)
//    with fused tanh (layer 0) or fused el/er attention logits (GAT layers).
//  - Aggregation: CSR by dst, single-pass unnormalized softmax accumulation
//    (divide by z at the end), 4 waves x float4 gathers per block.
// (Resubmission of round-1 kernel: previous bench hit GPUAcquisitionTimeout.)
// ---------------------------------------------------------------------------

typedef __attribute__((ext_vector_type(8))) short bf16x8;
typedef __attribute__((ext_vector_type(4))) float f32x4;

__device__ __forceinline__ void split2(float v, short& h, short& l) {
    __hip_bfloat16 bh = __float2bfloat16(v);
    float r = v - __bfloat162float(bh);
    __hip_bfloat16 bl = __float2bfloat16(r);
    h = *reinterpret_cast<short*>(&bh);
    l = *reinterpret_cast<short*>(&bl);
}

// ---------------- weight split: W[K,N] fp32 -> Bt_h/Bt_l [N,K] bf16 --------
__global__ __launch_bounds__(256) void wsplit_kernel(const float* __restrict__ W,
                                                     short* __restrict__ Bh,
                                                     short* __restrict__ Bl,
                                                     int K, int N) {
    int idx = blockIdx.x * 256 + threadIdx.x;
    if (idx >= K * N) return;
    int k = idx / N, n = idx - k * N;
    short h, l;
    split2(W[idx], h, l);
    Bh[n * K + k] = h;
    Bl[n * K + k] = l;
}

// ---------------- MFMA GEMM: C[M,256] = A[M,K] @ B[K,256] ------------------
// B supplied pre-split/transposed as Bh/Bl [256][K] bf16.
// Block 128x128, 256 threads (4 waves, 2x2 of 64x64), BK=32.
// TANH: apply tanh to C. ELER: also write el/er = head-dot with al/ar.
template<bool TANH, bool ELER>
__global__ __launch_bounds__(256, 2) void mfma_gemm_kernel(
        const float* __restrict__ A, const short* __restrict__ Bh,
        const short* __restrict__ Bl, float* __restrict__ C, int M, int K,
        const float* __restrict__ al, const float* __restrict__ ar,
        float* __restrict__ el, float* __restrict__ er) {
    __shared__ __align__(16) short As_h[128 * 32];
    __shared__ __align__(16) short As_l[128 * 32];
    __shared__ __align__(16) short Bs_h[128 * 32];
    __shared__ __align__(16) short Bs_l[128 * 32];

    const int tid = threadIdx.x;
    const int row0 = blockIdx.x * 128;
    const int col0 = blockIdx.y * 128;

    const int sr = tid >> 1;          // 0..127
    const int sc = (tid & 1) << 4;    // 0 or 16

    const int lane = tid & 63;
    const int lr = lane & 15;
    const int lg = lane >> 4;
    const int wid = tid >> 6;
    const int wm = wid >> 1;
    const int wn = wid & 1;

    f32x4 acc[4][4];
#pragma unroll
    for (int i = 0; i < 4; ++i)
#pragma unroll
        for (int j = 0; j < 4; ++j) acc[i][j] = (f32x4){0.f, 0.f, 0.f, 0.f};

    for (int k0 = 0; k0 < K; k0 += 32) {
        // stage A: rows row0..row0+127, cols k0..k0+31, split to bf16 h/l
        {
            float va[16];
            int g = row0 + sr;
            if (g < M) {
                const float4* ap = reinterpret_cast<const float4*>(&A[(size_t)g * K + k0 + sc]);
#pragma unroll
                for (int i = 0; i < 4; ++i) *reinterpret_cast<float4*>(&va[i * 4]) = ap[i];
            } else {
#pragma unroll
                for (int i = 0; i < 16; ++i) va[i] = 0.f;
            }
            short hs[16], ls[16];
#pragma unroll
            for (int i = 0; i < 16; ++i) split2(va[i], hs[i], ls[i]);
            *reinterpret_cast<bf16x8*>(&As_h[sr * 32 + sc])     = *reinterpret_cast<bf16x8*>(&hs[0]);
            *reinterpret_cast<bf16x8*>(&As_h[sr * 32 + sc + 8]) = *reinterpret_cast<bf16x8*>(&hs[8]);
            *reinterpret_cast<bf16x8*>(&As_l[sr * 32 + sc])     = *reinterpret_cast<bf16x8*>(&ls[0]);
            *reinterpret_cast<bf16x8*>(&As_l[sr * 32 + sc + 8]) = *reinterpret_cast<bf16x8*>(&ls[8]);
        }
        // stage B: Bh/Bl rows col0..col0+127, cols k0..k0+31 (already bf16)
        {
            const short* bhp = &Bh[(size_t)(col0 + sr) * K + k0 + sc];
            const short* blp = &Bl[(size_t)(col0 + sr) * K + k0 + sc];
            *reinterpret_cast<bf16x8*>(&Bs_h[sr * 32 + sc])     = *reinterpret_cast<const bf16x8*>(bhp);
            *reinterpret_cast<bf16x8*>(&Bs_h[sr * 32 + sc + 8]) = *reinterpret_cast<const bf16x8*>(bhp + 8);
            *reinterpret_cast<bf16x8*>(&Bs_l[sr * 32 + sc])     = *reinterpret_cast<const bf16x8*>(blp);
            *reinterpret_cast<bf16x8*>(&Bs_l[sr * 32 + sc + 8]) = *reinterpret_cast<const bf16x8*>(blp + 8);
        }
        __syncthreads();

        bf16x8 ah[4], av[4], bh[4], bv[4];
#pragma unroll
        for (int t = 0; t < 4; ++t) {
            int arow = (wm * 64 + t * 16 + lr) * 32 + lg * 8;
            int brow = (wn * 64 + t * 16 + lr) * 32 + lg * 8;
            ah[t] = *reinterpret_cast<const bf16x8*>(&As_h[arow]);
            av[t] = *reinterpret_cast<const bf16x8*>(&As_l[arow]);
            bh[t] = *reinterpret_cast<const bf16x8*>(&Bs_h[brow]);
            bv[t] = *reinterpret_cast<const bf16x8*>(&Bs_l[brow]);
        }
#pragma unroll
        for (int mt = 0; mt < 4; ++mt)
#pragma unroll
            for (int nt = 0; nt < 4; ++nt) {
                acc[mt][nt] = __builtin_amdgcn_mfma_f32_16x16x32_bf16(ah[mt], bh[nt], acc[mt][nt], 0, 0, 0);
                acc[mt][nt] = __builtin_amdgcn_mfma_f32_16x16x32_bf16(ah[mt], bv[nt], acc[mt][nt], 0, 0, 0);
                acc[mt][nt] = __builtin_amdgcn_mfma_f32_16x16x32_bf16(av[mt], bh[nt], acc[mt][nt], 0, 0, 0);
            }
        __syncthreads();
    }

    // epilogue: C write (+tanh), optional fused el/er (wave spans one head)
    const int head = blockIdx.y * 2 + wn;
    float alv[4], arv[4];
    if (ELER) {
#pragma unroll
        for (int nt = 0; nt < 4; ++nt) {
            alv[nt] = al[head * 64 + nt * 16 + lr];
            arv[nt] = ar[head * 64 + nt * 16 + lr];
        }
    }
#pragma unroll
    for (int mt = 0; mt < 4; ++mt) {
#pragma unroll
        for (int r = 0; r < 4; ++r) {
            int row = row0 + wm * 64 + mt * 16 + lg * 4 + r;
            bool valid = row < M;
            float sl = 0.f, sr_ = 0.f;
#pragma unroll
            for (int nt = 0; nt < 4; ++nt) {
                float v = acc[mt][nt][r];
                if (TANH) v = tanhf(v);
                if (valid) C[(size_t)row * 256 + col0 + wn * 64 + nt * 16 + lr] = v;
                if (ELER) { sl = fmaf(v, alv[nt], sl); sr_ = fmaf(v, arv[nt], sr_); }
            }
            if (ELER) {
#pragma unroll
                for (int mask = 1; mask < 16; mask <<= 1) {
                    sl  += __shfl_xor(sl, mask, 16);
                    sr_ += __shfl_xor(sr_, mask, 16);
                }
                if (valid && lr == 0) {
                    el[row * 4 + head] = sl;
                    er[row * 4 + head] = sr_;
                }
            }
        }
    }
}

// ---------------- CSR build ------------------------------------------------
__global__ void count_deg_kernel(const int* __restrict__ dst, int* __restrict__ deg, int E) {
    int i = blockIdx.x * blockDim.x + threadIdx.x;
    if (i < E) atomicAdd(&deg[dst[i]], 1);
}

__global__ __launch_bounds__(1024) void scan_kernel(const int* __restrict__ deg,
                                                    int* __restrict__ offs,
                                                    int* __restrict__ cursor, int n) {
    __shared__ int wsum[16];
    const int tid = threadIdx.x, lane = tid & 63, wv = tid >> 6;
    int carry = 0;
    for (int base = 0; base < n; base += 1024) {
        int i = base + tid;
        int v = (i < n) ? deg[i] : 0;
        int incl = v;
#pragma unroll
        for (int d = 1; d < 64; d <<= 1) {
            int t = __shfl_up(incl, d, 64);
            if (lane >= d) incl += t;
        }
        if (lane == 63) wsum[wv] = incl;
        __syncthreads();
        int woff = 0, tot = 0;
#pragma unroll
        for (int w2 = 0; w2 < 16; ++w2) {
            int s = wsum[w2];
            if (w2 < wv) woff += s;
            tot += s;
        }
        int excl = carry + woff + incl - v;
        if (i < n) { offs[i] = excl; cursor[i] = excl; }
        carry += tot;
        __syncthreads();
    }
    if (tid == 0) offs[n] = carry;
}

__global__ void fill_csr_kernel(const int* __restrict__ src, const int* __restrict__ dst,
                                int* __restrict__ cursor, int* __restrict__ srcs_sorted, int E) {
    int i = blockIdx.x * blockDim.x + threadIdx.x;
    if (i < E) {
        int d = dst[i];
        int pos = atomicAdd(&cursor[d], 1);
        srcs_sorted[pos] = src[i];
    }
}

// ---------------- GAT aggregation: single pass, 4 waves x float4 -----------
// Unnormalized softmax: acc = sum_e exp(sc_e)*feat[src_e], z = sum_e exp(sc_e);
// out = acc/z (+bias, ELU). Scores are O(1) so exp cannot overflow.
template<bool FINAL>
__global__ __launch_bounds__(256) void gat_agg_kernel(const float* __restrict__ feat,
                                                      const float* __restrict__ el,
                                                      const float* __restrict__ er,
                                                      const int* __restrict__ srcs,
                                                      const int* __restrict__ offs,
                                                      const float* __restrict__ bias,
                                                      float* __restrict__ out) {
    const int n = blockIdx.x;
    const int tid = threadIdx.x;
    const int w = tid >> 6, l = tid & 63;
    const int begin = offs[n], end = offs[n + 1];
    const int h = l >> 4;  // head of this lane's 4 channels
    const float erh = er[n * 4 + h];

    float4 acc = make_float4(0.f, 0.f, 0.f, 0.f);
    float z = 0.f;
    for (int p = begin + w; p < end; p += 4) {
        int s = srcs[p];
        float sc = el[s * 4 + h] + erh;
        sc = sc > 0.f ? sc : 0.2f * sc;
        float e = __expf(sc);
        z += e;
        const float4 f = *reinterpret_cast<const float4*>(&feat[(size_t)s * 256 + l * 4]);
        acc.x = fmaf(e, f.x, acc.x);
        acc.y = fmaf(e, f.y, acc.y);
        acc.z = fmaf(e, f.z, acc.z);
        acc.w = fmaf(e, f.w, acc.w);
    }

    __shared__ float s_acc[4][256];
    __shared__ float s_z[4][4];
    *reinterpret_cast<float4*>(&s_acc[w][l * 4]) = acc;
    if ((l & 15) == 0) s_z[w][h] = z;
    __syncthreads();

    const int c = tid;
    const int ch = c >> 6;
    float zs = s_z[0][ch] + s_z[1][ch] + s_z[2][ch] + s_z[3][ch];
    float vs = s_acc[0][c] + s_acc[1][c] + s_acc[2][c] + s_acc[3][c];
    float v = (zs > 0.f) ? vs / zs : 0.f;
    v += bias[c];
    v = v > 0.f ? v : expm1f(v);  // ELU

    if (!FINAL) {
        out[(size_t)n * 256 + c] = v;
    } else {
        __shared__ float s_v[256];
        s_v[c] = v;
        __syncthreads();
        if (tid < 64)
            out[(size_t)n * 64 + tid] =
                0.25f * (s_v[tid] + s_v[tid + 64] + s_v[tid + 128] + s_v[tid + 192]);
    }
}

// ---------------------------------------------------------------------------
extern "C" void kernel_launch(void* const* d_in, const int* in_sizes, int n_in,
                              void* d_out, int out_size, void* d_ws, size_t ws_size,
                              hipStream_t stream) {
    const float* x_feat = (const float*)d_in[0];
    const float* W_fc   = (const float*)d_in[1];
    const float* W1     = (const float*)d_in[2];
    const float* al1    = (const float*)d_in[3];
    const float* ar1    = (const float*)d_in[4];
    const float* b1     = (const float*)d_in[5];
    const float* W2     = (const float*)d_in[6];
    const float* al2    = (const float*)d_in[7];
    const float* ar2    = (const float*)d_in[8];
    const float* b2     = (const float*)d_in[9];
    const int*   src    = (const int*)d_in[10];
    const int*   dst    = (const int*)d_in[11];
    float* out = (float*)d_out;

    const int N = in_sizes[0] / 128;   // 50000
    const int E = in_sizes[10];        // 800000

    char* ws = (char*)d_ws;
    size_t off = 0;
    auto alloc = [&](size_t bytes) -> void* {
        off = (off + 255) & ~(size_t)255;
        void* p = ws + off;
        off += bytes;
        return p;
    };
    float* buf0 = (float*)alloc((size_t)N * 256 * 4);  // h, later g1
    float* buf1 = (float*)alloc((size_t)N * 256 * 4);  // feat1, later feat2
    float* el   = (float*)alloc((size_t)N * 4 * 4);
    float* er   = (float*)alloc((size_t)N * 4 * 4);
    int* deg    = (int*)alloc((size_t)N * 4);
    int* offs   = (int*)alloc((size_t)(N + 1) * 4);
    int* cursor = (int*)alloc((size_t)N * 4);
    int* srcs_sorted = (int*)alloc((size_t)E * 4);
    short* Bfc_h = (short*)alloc((size_t)256 * 128 * 2);
    short* Bfc_l = (short*)alloc((size_t)256 * 128 * 2);
    short* B1_h  = (short*)alloc((size_t)256 * 256 * 2);
    short* B1_l  = (short*)alloc((size_t)256 * 256 * 2);
    short* B2_h  = (short*)alloc((size_t)256 * 256 * 2);
    short* B2_l  = (short*)alloc((size_t)256 * 256 * 2);

    const int eb = (E + 255) / 256;
    dim3 ggrid((N + 127) / 128, 2);

    // CSR build (by dst)
    hipMemsetAsync(deg, 0, (size_t)N * 4, stream);
    count_deg_kernel<<<eb, 256, 0, stream>>>(dst, deg, E);
    scan_kernel<<<1, 1024, 0, stream>>>(deg, offs, cursor, N);
    fill_csr_kernel<<<eb, 256, 0, stream>>>(src, dst, cursor, srcs_sorted, E);

    // weight splits
    wsplit_kernel<<<(128 * 256 + 255) / 256, 256, 0, stream>>>(W_fc, Bfc_h, Bfc_l, 128, 256);
    wsplit_kernel<<<(256 * 256 + 255) / 256, 256, 0, stream>>>(W1, B1_h, B1_l, 256, 256);
    wsplit_kernel<<<(256 * 256 + 255) / 256, 256, 0, stream>>>(W2, B2_h, B2_l, 256, 256);

    // h = tanh(x @ W_fc)
    mfma_gemm_kernel<true, false><<<ggrid, 256, 0, stream>>>(
        x_feat, Bfc_h, Bfc_l, buf0, N, 128, nullptr, nullptr, nullptr, nullptr);
    // feat1 = h @ W1 (+ el/er)
    mfma_gemm_kernel<false, true><<<ggrid, 256, 0, stream>>>(
        buf0, B1_h, B1_l, buf1, N, 256, al1, ar1, el, er);
    // g1 -> buf0
    gat_agg_kernel<false><<<N, 256, 0, stream>>>(buf1, el, er, srcs_sorted, offs, b1, buf0);
    // feat2 = g1 @ W2 (+ el/er)
    mfma_gemm_kernel<false, true><<<ggrid, 256, 0, stream>>>(
        buf0, B2_h, B2_l, buf1, N, 256, al2, ar2, el, er);
    // final aggregation + head mean -> out
    gat_agg_kernel<true><<<N, 256, 0, stream>>>(buf1, el, er, srcs_sorted, offs, b2, out);
}

// Round 4
// 565.529 us; speedup vs baseline: 1.8418x; 1.0250x over previous
//
#include <hip/hip_runtime.h>
#include <hip/hip_bf16.h>
#include <math.h>

// ---------------------------------------------------------------------------
// HomoGAT on MI355X.
//  - GEMMs: split-precision bf16 MFMA (A=Ah+Al, B=Bh+Bl, 3 products, fp32 acc)
//    with fused fast-tanh (layer 0) or fused el/er attention logits.
//  - Aggregation: CSR by dst, wave-per-node, unrolled-by-4 gather for MLP,
//    single-pass unnormalized softmax (scores O(1), no overflow), no LDS.
// ---------------------------------------------------------------------------

typedef __attribute__((ext_vector_type(8))) short bf16x8;
typedef __attribute__((ext_vector_type(4))) float f32x4;

__device__ __forceinline__ void split2(float v, short& h, short& l) {
    __hip_bfloat16 bh = __float2bfloat16(v);
    float r = v - __bfloat162float(bh);
    __hip_bfloat16 bl = __float2bfloat16(r);
    h = *reinterpret_cast<short*>(&bh);
    l = *reinterpret_cast<short*>(&bl);
}

__device__ __forceinline__ float fast_tanh(float x) {
    x = fminf(fmaxf(x, -15.f), 15.f);
    float e = __expf(2.f * x);
    return (e - 1.f) * __builtin_amdgcn_rcpf(e + 1.f);
}

// ---------------- weight split: W[K,N] fp32 -> Bt_h/Bt_l [N,K] bf16 --------
__global__ __launch_bounds__(256) void wsplit_kernel(const float* __restrict__ W,
                                                     short* __restrict__ Bh,
                                                     short* __restrict__ Bl,
                                                     int K, int N) {
    int idx = blockIdx.x * 256 + threadIdx.x;
    if (idx >= K * N) return;
    int k = idx / N, n = idx - k * N;
    short h, l;
    split2(W[idx], h, l);
    Bh[n * K + k] = h;
    Bl[n * K + k] = l;
}

// ---------------- MFMA GEMM: C[M,256] = A[M,K] @ B[K,256] ------------------
// B supplied pre-split/transposed as Bh/Bl [256][K] bf16.
// Block 128x128, 256 threads (4 waves, 2x2 of 64x64), BK=32.
// TANH: apply tanh to C. ELER: also write el/er = head-dot with al/ar.
template<bool TANH, bool ELER>
__global__ __launch_bounds__(256, 2) void mfma_gemm_kernel(
        const float* __restrict__ A, const short* __restrict__ Bh,
        const short* __restrict__ Bl, float* __restrict__ C, int M, int K,
        const float* __restrict__ al, const float* __restrict__ ar,
        float* __restrict__ el, float* __restrict__ er) {
    __shared__ __align__(16) short As_h[128 * 32];
    __shared__ __align__(16) short As_l[128 * 32];
    __shared__ __align__(16) short Bs_h[128 * 32];
    __shared__ __align__(16) short Bs_l[128 * 32];

    const int tid = threadIdx.x;
    const int row0 = blockIdx.x * 128;
    const int col0 = blockIdx.y * 128;

    const int sr = tid >> 1;          // 0..127
    const int sc = (tid & 1) << 4;    // 0 or 16

    const int lane = tid & 63;
    const int lr = lane & 15;
    const int lg = lane >> 4;
    const int wid = tid >> 6;
    const int wm = wid >> 1;
    const int wn = wid & 1;

    f32x4 acc[4][4];
#pragma unroll
    for (int i = 0; i < 4; ++i)
#pragma unroll
        for (int j = 0; j < 4; ++j) acc[i][j] = (f32x4){0.f, 0.f, 0.f, 0.f};

    for (int k0 = 0; k0 < K; k0 += 32) {
        // stage A: rows row0..row0+127, cols k0..k0+31, split to bf16 h/l
        {
            float va[16];
            int g = row0 + sr;
            if (g < M) {
                const float4* ap = reinterpret_cast<const float4*>(&A[(size_t)g * K + k0 + sc]);
#pragma unroll
                for (int i = 0; i < 4; ++i) *reinterpret_cast<float4*>(&va[i * 4]) = ap[i];
            } else {
#pragma unroll
                for (int i = 0; i < 16; ++i) va[i] = 0.f;
            }
            short hs[16], ls[16];
#pragma unroll
            for (int i = 0; i < 16; ++i) split2(va[i], hs[i], ls[i]);
            *reinterpret_cast<bf16x8*>(&As_h[sr * 32 + sc])     = *reinterpret_cast<bf16x8*>(&hs[0]);
            *reinterpret_cast<bf16x8*>(&As_h[sr * 32 + sc + 8]) = *reinterpret_cast<bf16x8*>(&hs[8]);
            *reinterpret_cast<bf16x8*>(&As_l[sr * 32 + sc])     = *reinterpret_cast<bf16x8*>(&ls[0]);
            *reinterpret_cast<bf16x8*>(&As_l[sr * 32 + sc + 8]) = *reinterpret_cast<bf16x8*>(&ls[8]);
        }
        // stage B: Bh/Bl rows col0..col0+127, cols k0..k0+31 (already bf16)
        {
            const short* bhp = &Bh[(size_t)(col0 + sr) * K + k0 + sc];
            const short* blp = &Bl[(size_t)(col0 + sr) * K + k0 + sc];
            *reinterpret_cast<bf16x8*>(&Bs_h[sr * 32 + sc])     = *reinterpret_cast<const bf16x8*>(bhp);
            *reinterpret_cast<bf16x8*>(&Bs_h[sr * 32 + sc + 8]) = *reinterpret_cast<const bf16x8*>(bhp + 8);
            *reinterpret_cast<bf16x8*>(&Bs_l[sr * 32 + sc])     = *reinterpret_cast<const bf16x8*>(blp);
            *reinterpret_cast<bf16x8*>(&Bs_l[sr * 32 + sc + 8]) = *reinterpret_cast<const bf16x8*>(blp + 8);
        }
        __syncthreads();

        bf16x8 ah[4], av[4], bh[4], bv[4];
#pragma unroll
        for (int t = 0; t < 4; ++t) {
            int arow = (wm * 64 + t * 16 + lr) * 32 + lg * 8;
            int brow = (wn * 64 + t * 16 + lr) * 32 + lg * 8;
            ah[t] = *reinterpret_cast<const bf16x8*>(&As_h[arow]);
            av[t] = *reinterpret_cast<const bf16x8*>(&As_l[arow]);
            bh[t] = *reinterpret_cast<const bf16x8*>(&Bs_h[brow]);
            bv[t] = *reinterpret_cast<const bf16x8*>(&Bs_l[brow]);
        }
#pragma unroll
        for (int mt = 0; mt < 4; ++mt)
#pragma unroll
            for (int nt = 0; nt < 4; ++nt) {
                acc[mt][nt] = __builtin_amdgcn_mfma_f32_16x16x32_bf16(ah[mt], bh[nt], acc[mt][nt], 0, 0, 0);
                acc[mt][nt] = __builtin_amdgcn_mfma_f32_16x16x32_bf16(ah[mt], bv[nt], acc[mt][nt], 0, 0, 0);
                acc[mt][nt] = __builtin_amdgcn_mfma_f32_16x16x32_bf16(av[mt], bh[nt], acc[mt][nt], 0, 0, 0);
            }
        __syncthreads();
    }

    // epilogue: C write (+tanh), optional fused el/er (wave spans one head)
    const int head = blockIdx.y * 2 + wn;
    float alv[4], arv[4];
    if (ELER) {
#pragma unroll
        for (int nt = 0; nt < 4; ++nt) {
            alv[nt] = al[head * 64 + nt * 16 + lr];
            arv[nt] = ar[head * 64 + nt * 16 + lr];
        }
    }
#pragma unroll
    for (int mt = 0; mt < 4; ++mt) {
#pragma unroll
        for (int r = 0; r < 4; ++r) {
            int row = row0 + wm * 64 + mt * 16 + lg * 4 + r;
            bool valid = row < M;
            float sl = 0.f, sr_ = 0.f;
#pragma unroll
            for (int nt = 0; nt < 4; ++nt) {
                float v = acc[mt][nt][r];
                if (TANH) v = fast_tanh(v);
                if (valid) C[(size_t)row * 256 + col0 + wn * 64 + nt * 16 + lr] = v;
                if (ELER) { sl = fmaf(v, alv[nt], sl); sr_ = fmaf(v, arv[nt], sr_); }
            }
            if (ELER) {
#pragma unroll
                for (int mask = 1; mask < 16; mask <<= 1) {
                    sl  += __shfl_xor(sl, mask, 16);
                    sr_ += __shfl_xor(sr_, mask, 16);
                }
                if (valid && lr == 0) {
                    el[row * 4 + head] = sl;
                    er[row * 4 + head] = sr_;
                }
            }
        }
    }
}

// ---------------- CSR build ------------------------------------------------
__global__ void count_deg_kernel(const int* __restrict__ dst, int* __restrict__ deg, int E) {
    int i = blockIdx.x * blockDim.x + threadIdx.x;
    if (i < E) atomicAdd(&deg[dst[i]], 1);
}

__global__ __launch_bounds__(1024) void scan_kernel(const int* __restrict__ deg,
                                                    int* __restrict__ offs,
                                                    int* __restrict__ cursor, int n) {
    __shared__ int wsum[16];
    const int tid = threadIdx.x, lane = tid & 63, wv = tid >> 6;
    int carry = 0;
    for (int base = 0; base < n; base += 1024) {
        int i = base + tid;
        int v = (i < n) ? deg[i] : 0;
        int incl = v;
#pragma unroll
        for (int d = 1; d < 64; d <<= 1) {
            int t = __shfl_up(incl, d, 64);
            if (lane >= d) incl += t;
        }
        if (lane == 63) wsum[wv] = incl;
        __syncthreads();
        int woff = 0, tot = 0;
#pragma unroll
        for (int w2 = 0; w2 < 16; ++w2) {
            int s = wsum[w2];
            if (w2 < wv) woff += s;
            tot += s;
        }
        int excl = carry + woff + incl - v;
        if (i < n) { offs[i] = excl; cursor[i] = excl; }
        carry += tot;
        __syncthreads();
    }
    if (tid == 0) offs[n] = carry;
}

__global__ void fill_csr_kernel(const int* __restrict__ src, const int* __restrict__ dst,
                                int* __restrict__ cursor, int* __restrict__ srcs_sorted, int E) {
    int i = blockIdx.x * blockDim.x + threadIdx.x;
    if (i < E) {
        int d = dst[i];
        int pos = atomicAdd(&cursor[d], 1);
        srcs_sorted[pos] = src[i];
    }
}

// ---------------- GAT aggregation: wave per node, unroll-4 gather ----------
// Each wave owns one dst node; 64 lanes = full 256-channel row (float4/lane).
// Single-pass unnormalized softmax; per-head z computed redundantly per lane
// (identical within each 16-lane group) -> no LDS, no barriers, no reduce.
template<bool FINAL>
__global__ __launch_bounds__(256) void gat_agg_kernel(const float* __restrict__ feat,
                                                      const float* __restrict__ el,
                                                      const float* __restrict__ er,
                                                      const int* __restrict__ srcs,
                                                      const int* __restrict__ offs,
                                                      const float* __restrict__ bias,
                                                      float* __restrict__ out, int N) {
    const int tid = threadIdx.x;
    const int w = tid >> 6, l = tid & 63;
    const int n = blockIdx.x * 4 + w;
    if (n >= N) return;
    const int h = l >> 4;                // head of this lane's 4 channels
    const int begin = offs[n];
    const int deg = offs[n + 1] - begin;
    const float erh = er[n * 4 + h];

    float4 acc = make_float4(0.f, 0.f, 0.f, 0.f);
    float z = 0.f;

    for (int base = 0; base < deg; base += 64) {
        const int cnt = min(64, deg - base);
        int myidx = 0;
        if (base + l < deg) myidx = srcs[begin + base + l];
        for (int j = 0; j < cnt; j += 4) {
            const int s0 = __shfl(myidx, j + 0, 64);
            const int s1 = __shfl(myidx, j + 1, 64);
            const int s2 = __shfl(myidx, j + 2, 64);
            const int s3 = __shfl(myidx, j + 3, 64);
            // issue all loads up-front (independent -> 8 in flight)
            const float el0 = el[s0 * 4 + h];
            const float el1 = el[s1 * 4 + h];
            const float el2 = el[s2 * 4 + h];
            const float el3 = el[s3 * 4 + h];
            const float4 f0 = *reinterpret_cast<const float4*>(&feat[(size_t)s0 * 256 + l * 4]);
            const float4 f1 = *reinterpret_cast<const float4*>(&feat[(size_t)s1 * 256 + l * 4]);
            const float4 f2 = *reinterpret_cast<const float4*>(&feat[(size_t)s2 * 256 + l * 4]);
            const float4 f3 = *reinterpret_cast<const float4*>(&feat[(size_t)s3 * 256 + l * 4]);
            float t0 = el0 + erh; t0 = t0 > 0.f ? t0 : 0.2f * t0;
            float t1 = el1 + erh; t1 = t1 > 0.f ? t1 : 0.2f * t1;
            float t2 = el2 + erh; t2 = t2 > 0.f ? t2 : 0.2f * t2;
            float t3 = el3 + erh; t3 = t3 > 0.f ? t3 : 0.2f * t3;
            float e0 = __expf(t0);
            float e1 = (j + 1 < cnt) ? __expf(t1) : 0.f;
            float e2 = (j + 2 < cnt) ? __expf(t2) : 0.f;
            float e3 = (j + 3 < cnt) ? __expf(t3) : 0.f;
            z += e0 + e1 + e2 + e3;
            acc.x = fmaf(e0, f0.x, acc.x); acc.y = fmaf(e0, f0.y, acc.y);
            acc.z = fmaf(e0, f0.z, acc.z); acc.w = fmaf(e0, f0.w, acc.w);
            acc.x = fmaf(e1, f1.x, acc.x); acc.y = fmaf(e1, f1.y, acc.y);
            acc.z = fmaf(e1, f1.z, acc.z); acc.w = fmaf(e1, f1.w, acc.w);
            acc.x = fmaf(e2, f2.x, acc.x); acc.y = fmaf(e2, f2.y, acc.y);
            acc.z = fmaf(e2, f2.z, acc.z); acc.w = fmaf(e2, f2.w, acc.w);
            acc.x = fmaf(e3, f3.x, acc.x); acc.y = fmaf(e3, f3.y, acc.y);
            acc.z = fmaf(e3, f3.z, acc.z); acc.w = fmaf(e3, f3.w, acc.w);
        }
    }

    const float rz = (z > 0.f) ? __builtin_amdgcn_rcpf(z) : 0.f;
    const float4 bv = *reinterpret_cast<const float4*>(&bias[l * 4]);
    float4 v;
    v.x = fmaf(acc.x, rz, bv.x);
    v.y = fmaf(acc.y, rz, bv.y);
    v.z = fmaf(acc.z, rz, bv.z);
    v.w = fmaf(acc.w, rz, bv.w);
    v.x = v.x > 0.f ? v.x : expm1f(v.x);
    v.y = v.y > 0.f ? v.y : expm1f(v.y);
    v.z = v.z > 0.f ? v.z : expm1f(v.z);
    v.w = v.w > 0.f ? v.w : expm1f(v.w);

    if (!FINAL) {
        *reinterpret_cast<float4*>(&out[(size_t)n * 256 + l * 4]) = v;
    } else {
        // mean over heads: sum lanes l, l+16, l+32, l+48 then /4
        v.x += __shfl_down(v.x, 32, 64); v.y += __shfl_down(v.y, 32, 64);
        v.z += __shfl_down(v.z, 32, 64); v.w += __shfl_down(v.w, 32, 64);
        v.x += __shfl_down(v.x, 16, 64); v.y += __shfl_down(v.y, 16, 64);
        v.z += __shfl_down(v.z, 16, 64); v.w += __shfl_down(v.w, 16, 64);
        if (l < 16) {
            float4 o;
            o.x = 0.25f * v.x; o.y = 0.25f * v.y; o.z = 0.25f * v.z; o.w = 0.25f * v.w;
            *reinterpret_cast<float4*>(&out[(size_t)n * 64 + l * 4]) = o;
        }
    }
}

// ---------------------------------------------------------------------------
extern "C" void kernel_launch(void* const* d_in, const int* in_sizes, int n_in,
                              void* d_out, int out_size, void* d_ws, size_t ws_size,
                              hipStream_t stream) {
    const float* x_feat = (const float*)d_in[0];
    const float* W_fc   = (const float*)d_in[1];
    const float* W1     = (const float*)d_in[2];
    const float* al1    = (const float*)d_in[3];
    const float* ar1    = (const float*)d_in[4];
    const float* b1     = (const float*)d_in[5];
    const float* W2     = (const float*)d_in[6];
    const float* al2    = (const float*)d_in[7];
    const float* ar2    = (const float*)d_in[8];
    const float* b2     = (const float*)d_in[9];
    const int*   src    = (const int*)d_in[10];
    const int*   dst    = (const int*)d_in[11];
    float* out = (float*)d_out;

    const int N = in_sizes[0] / 128;   // 50000
    const int E = in_sizes[10];        // 800000

    char* ws = (char*)d_ws;
    size_t off = 0;
    auto alloc = [&](size_t bytes) -> void* {
        off = (off + 255) & ~(size_t)255;
        void* p = ws + off;
        off += bytes;
        return p;
    };
    float* buf0 = (float*)alloc((size_t)N * 256 * 4);  // h, later g1
    float* buf1 = (float*)alloc((size_t)N * 256 * 4);  // feat1, later feat2
    float* el   = (float*)alloc((size_t)N * 4 * 4);
    float* er   = (float*)alloc((size_t)N * 4 * 4);
    int* deg    = (int*)alloc((size_t)N * 4);
    int* offs   = (int*)alloc((size_t)(N + 1) * 4);
    int* cursor = (int*)alloc((size_t)N * 4);
    int* srcs_sorted = (int*)alloc((size_t)E * 4);
    short* Bfc_h = (short*)alloc((size_t)256 * 128 * 2);
    short* Bfc_l = (short*)alloc((size_t)256 * 128 * 2);
    short* B1_h  = (short*)alloc((size_t)256 * 256 * 2);
    short* B1_l  = (short*)alloc((size_t)256 * 256 * 2);
    short* B2_h  = (short*)alloc((size_t)256 * 256 * 2);
    short* B2_l  = (short*)alloc((size_t)256 * 256 * 2);

    const int eb = (E + 255) / 256;
    dim3 ggrid((N + 127) / 128, 2);
    const int agrid = (N + 3) / 4;

    // CSR build (by dst)
    hipMemsetAsync(deg, 0, (size_t)N * 4, stream);
    count_deg_kernel<<<eb, 256, 0, stream>>>(dst, deg, E);
    scan_kernel<<<1, 1024, 0, stream>>>(deg, offs, cursor, N);
    fill_csr_kernel<<<eb, 256, 0, stream>>>(src, dst, cursor, srcs_sorted, E);

    // weight splits
    wsplit_kernel<<<(128 * 256 + 255) / 256, 256, 0, stream>>>(W_fc, Bfc_h, Bfc_l, 128, 256);
    wsplit_kernel<<<(256 * 256 + 255) / 256, 256, 0, stream>>>(W1, B1_h, B1_l, 256, 256);
    wsplit_kernel<<<(256 * 256 + 255) / 256, 256, 0, stream>>>(W2, B2_h, B2_l, 256, 256);

    // h = tanh(x @ W_fc)
    mfma_gemm_kernel<true, false><<<ggrid, 256, 0, stream>>>(
        x_feat, Bfc_h, Bfc_l, buf0, N, 128, nullptr, nullptr, nullptr, nullptr);
    // feat1 = h @ W1 (+ el/er)
    mfma_gemm_kernel<false, true><<<ggrid, 256, 0, stream>>>(
        buf0, B1_h, B1_l, buf1, N, 256, al1, ar1, el, er);
    // g1 -> buf0
    gat_agg_kernel<false><<<agrid, 256, 0, stream>>>(buf1, el, er, srcs_sorted, offs, b1, buf0, N);
    // feat2 = g1 @ W2 (+ el/er)
    mfma_gemm_kernel<false, true><<<ggrid, 256, 0, stream>>>(
        buf0, B2_h, B2_l, buf1, N, 256, al2, ar2, el, er);
    // final aggregation + head mean -> out
    gat_agg_kernel<true><<<agrid, 256, 0, stream>>>(buf1, el, er, srcs_sorted, offs, b2, out, N);
}

// Round 5
// 550.490 us; speedup vs baseline: 1.8921x; 1.0273x over previous
//
#include <hip/hip_runtime.h>
#include <hip/hip_bf16.h>
#include <math.h>

// ---------------------------------------------------------------------------
// HomoGAT on MI355X.
//  - GEMMs: split-precision bf16 MFMA (A=Ah+Al, B=Bh+Bl, 3 products, fp32 acc)
//    with fused fast-tanh (layer 0) or fused el/er attention logits.
//  - Aggregation: CSR by dst, wave-per-node. Edge indices + el rows go through
//    the SCALAR path (wave-uniform); inner loop issues only 8 independent
//    feat-row dwordx4 loads -> max VMEM concurrency per wave.
// ---------------------------------------------------------------------------

typedef __attribute__((ext_vector_type(8))) short bf16x8;
typedef __attribute__((ext_vector_type(4))) float f32x4;

__device__ __forceinline__ void split2(float v, short& h, short& l) {
    __hip_bfloat16 bh = __float2bfloat16(v);
    float r = v - __bfloat162float(bh);
    __hip_bfloat16 bl = __float2bfloat16(r);
    h = *reinterpret_cast<short*>(&bh);
    l = *reinterpret_cast<short*>(&bl);
}

__device__ __forceinline__ float fast_tanh(float x) {
    x = fminf(fmaxf(x, -15.f), 15.f);
    float e = __expf(2.f * x);
    return (e - 1.f) * __builtin_amdgcn_rcpf(e + 1.f);
}

__device__ __forceinline__ float sel_head(float4 q, int h) {
    float lo = (h & 1) ? q.y : q.x;
    float hi = (h & 1) ? q.w : q.z;
    return (h & 2) ? hi : lo;
}

// ---------------- weight split: W[K,N] fp32 -> Bt_h/Bt_l [N,K] bf16 --------
__global__ __launch_bounds__(256) void wsplit_kernel(const float* __restrict__ W,
                                                     short* __restrict__ Bh,
                                                     short* __restrict__ Bl,
                                                     int K, int N) {
    int idx = blockIdx.x * 256 + threadIdx.x;
    if (idx >= K * N) return;
    int k = idx / N, n = idx - k * N;
    short h, l;
    split2(W[idx], h, l);
    Bh[n * K + k] = h;
    Bl[n * K + k] = l;
}

// ---------------- MFMA GEMM: C[M,256] = A[M,K] @ B[K,256] ------------------
// B supplied pre-split/transposed as Bh/Bl [256][K] bf16.
// Block 128x128, 256 threads (4 waves, 2x2 of 64x64), BK=32.
// TANH: apply tanh to C. ELER: also write el/er = head-dot with al/ar.
template<bool TANH, bool ELER>
__global__ __launch_bounds__(256, 2) void mfma_gemm_kernel(
        const float* __restrict__ A, const short* __restrict__ Bh,
        const short* __restrict__ Bl, float* __restrict__ C, int M, int K,
        const float* __restrict__ al, const float* __restrict__ ar,
        float* __restrict__ el, float* __restrict__ er) {
    __shared__ __align__(16) short As_h[128 * 32];
    __shared__ __align__(16) short As_l[128 * 32];
    __shared__ __align__(16) short Bs_h[128 * 32];
    __shared__ __align__(16) short Bs_l[128 * 32];

    const int tid = threadIdx.x;
    const int row0 = blockIdx.x * 128;
    const int col0 = blockIdx.y * 128;

    const int sr = tid >> 1;          // 0..127
    const int sc = (tid & 1) << 4;    // 0 or 16

    const int lane = tid & 63;
    const int lr = lane & 15;
    const int lg = lane >> 4;
    const int wid = tid >> 6;
    const int wm = wid >> 1;
    const int wn = wid & 1;

    f32x4 acc[4][4];
#pragma unroll
    for (int i = 0; i < 4; ++i)
#pragma unroll
        for (int j = 0; j < 4; ++j) acc[i][j] = (f32x4){0.f, 0.f, 0.f, 0.f};

    for (int k0 = 0; k0 < K; k0 += 32) {
        // stage A: rows row0..row0+127, cols k0..k0+31, split to bf16 h/l
        {
            float va[16];
            int g = row0 + sr;
            if (g < M) {
                const float4* ap = reinterpret_cast<const float4*>(&A[(size_t)g * K + k0 + sc]);
#pragma unroll
                for (int i = 0; i < 4; ++i) *reinterpret_cast<float4*>(&va[i * 4]) = ap[i];
            } else {
#pragma unroll
                for (int i = 0; i < 16; ++i) va[i] = 0.f;
            }
            short hs[16], ls[16];
#pragma unroll
            for (int i = 0; i < 16; ++i) split2(va[i], hs[i], ls[i]);
            *reinterpret_cast<bf16x8*>(&As_h[sr * 32 + sc])     = *reinterpret_cast<bf16x8*>(&hs[0]);
            *reinterpret_cast<bf16x8*>(&As_h[sr * 32 + sc + 8]) = *reinterpret_cast<bf16x8*>(&hs[8]);
            *reinterpret_cast<bf16x8*>(&As_l[sr * 32 + sc])     = *reinterpret_cast<bf16x8*>(&ls[0]);
            *reinterpret_cast<bf16x8*>(&As_l[sr * 32 + sc + 8]) = *reinterpret_cast<bf16x8*>(&ls[8]);
        }
        // stage B: Bh/Bl rows col0..col0+127, cols k0..k0+31 (already bf16)
        {
            const short* bhp = &Bh[(size_t)(col0 + sr) * K + k0 + sc];
            const short* blp = &Bl[(size_t)(col0 + sr) * K + k0 + sc];
            *reinterpret_cast<bf16x8*>(&Bs_h[sr * 32 + sc])     = *reinterpret_cast<const bf16x8*>(bhp);
            *reinterpret_cast<bf16x8*>(&Bs_h[sr * 32 + sc + 8]) = *reinterpret_cast<const bf16x8*>(bhp + 8);
            *reinterpret_cast<bf16x8*>(&Bs_l[sr * 32 + sc])     = *reinterpret_cast<const bf16x8*>(blp);
            *reinterpret_cast<bf16x8*>(&Bs_l[sr * 32 + sc + 8]) = *reinterpret_cast<const bf16x8*>(blp + 8);
        }
        __syncthreads();

        bf16x8 ah[4], av[4], bh[4], bv[4];
#pragma unroll
        for (int t = 0; t < 4; ++t) {
            int arow = (wm * 64 + t * 16 + lr) * 32 + lg * 8;
            int brow = (wn * 64 + t * 16 + lr) * 32 + lg * 8;
            ah[t] = *reinterpret_cast<const bf16x8*>(&As_h[arow]);
            av[t] = *reinterpret_cast<const bf16x8*>(&As_l[arow]);
            bh[t] = *reinterpret_cast<const bf16x8*>(&Bs_h[brow]);
            bv[t] = *reinterpret_cast<const bf16x8*>(&Bs_l[brow]);
        }
#pragma unroll
        for (int mt = 0; mt < 4; ++mt)
#pragma unroll
            for (int nt = 0; nt < 4; ++nt) {
                acc[mt][nt] = __builtin_amdgcn_mfma_f32_16x16x32_bf16(ah[mt], bh[nt], acc[mt][nt], 0, 0, 0);
                acc[mt][nt] = __builtin_amdgcn_mfma_f32_16x16x32_bf16(ah[mt], bv[nt], acc[mt][nt], 0, 0, 0);
                acc[mt][nt] = __builtin_amdgcn_mfma_f32_16x16x32_bf16(av[mt], bh[nt], acc[mt][nt], 0, 0, 0);
            }
        __syncthreads();
    }

    // epilogue: C write (+tanh), optional fused el/er (wave spans one head)
    const int head = blockIdx.y * 2 + wn;
    float alv[4], arv[4];
    if (ELER) {
#pragma unroll
        for (int nt = 0; nt < 4; ++nt) {
            alv[nt] = al[head * 64 + nt * 16 + lr];
            arv[nt] = ar[head * 64 + nt * 16 + lr];
        }
    }
#pragma unroll
    for (int mt = 0; mt < 4; ++mt) {
#pragma unroll
        for (int r = 0; r < 4; ++r) {
            int row = row0 + wm * 64 + mt * 16 + lg * 4 + r;
            bool valid = row < M;
            float sl = 0.f, sr_ = 0.f;
#pragma unroll
            for (int nt = 0; nt < 4; ++nt) {
                float v = acc[mt][nt][r];
                if (TANH) v = fast_tanh(v);
                if (valid) C[(size_t)row * 256 + col0 + wn * 64 + nt * 16 + lr] = v;
                if (ELER) { sl = fmaf(v, alv[nt], sl); sr_ = fmaf(v, arv[nt], sr_); }
            }
            if (ELER) {
#pragma unroll
                for (int mask = 1; mask < 16; mask <<= 1) {
                    sl  += __shfl_xor(sl, mask, 16);
                    sr_ += __shfl_xor(sr_, mask, 16);
                }
                if (valid && lr == 0) {
                    el[row * 4 + head] = sl;
                    er[row * 4 + head] = sr_;
                }
            }
        }
    }
}

// ---------------- CSR build ------------------------------------------------
__global__ void count_deg_kernel(const int* __restrict__ dst, int* __restrict__ deg, int E) {
    int i = blockIdx.x * blockDim.x + threadIdx.x;
    if (i < E) atomicAdd(&deg[dst[i]], 1);
}

__global__ __launch_bounds__(1024) void scan_kernel(const int* __restrict__ deg,
                                                    int* __restrict__ offs,
                                                    int* __restrict__ cursor, int n) {
    __shared__ int wsum[16];
    const int tid = threadIdx.x, lane = tid & 63, wv = tid >> 6;
    int carry = 0;
    for (int base = 0; base < n; base += 1024) {
        int i = base + tid;
        int v = (i < n) ? deg[i] : 0;
        int incl = v;
#pragma unroll
        for (int d = 1; d < 64; d <<= 1) {
            int t = __shfl_up(incl, d, 64);
            if (lane >= d) incl += t;
        }
        if (lane == 63) wsum[wv] = incl;
        __syncthreads();
        int woff = 0, tot = 0;
#pragma unroll
        for (int w2 = 0; w2 < 16; ++w2) {
            int s = wsum[w2];
            if (w2 < wv) woff += s;
            tot += s;
        }
        int excl = carry + woff + incl - v;
        if (i < n) { offs[i] = excl; cursor[i] = excl; }
        carry += tot;
        __syncthreads();
    }
    if (tid == 0) offs[n] = carry;
}

__global__ void fill_csr_kernel(const int* __restrict__ src, const int* __restrict__ dst,
                                int* __restrict__ cursor, int* __restrict__ srcs_sorted, int E) {
    int i = blockIdx.x * blockDim.x + threadIdx.x;
    if (i < E) {
        int d = dst[i];
        int pos = atomicAdd(&cursor[d], 1);
        srcs_sorted[pos] = src[i];
    }
}

// ---------------- GAT aggregation: wave/node, scalar idx+el, 8 rows inflight
// Each wave owns one dst node; 64 lanes = full 256-channel row (float4/lane).
// Edge indices and el rows are wave-uniform -> scalar path (s_load); the
// vector memory queue carries only the 8 independent feat-row loads.
template<bool FINAL>
__global__ __launch_bounds__(256) void gat_agg_kernel(const float* __restrict__ feat,
                                                      const float* __restrict__ el,
                                                      const float* __restrict__ er,
                                                      const int* __restrict__ srcs,
                                                      const int* __restrict__ offs,
                                                      const float* __restrict__ bias,
                                                      float* __restrict__ out, int N) {
    const int tid = threadIdx.x;
    const int w = tid >> 6, l = tid & 63;
    const int n = blockIdx.x * 4 + w;
    if (n >= N) return;
    const int h = l >> 4;                // head of this lane's 4 channels
    const int begin = offs[n];
    const int deg = offs[n + 1] - begin;
    const float erh = er[n * 4 + h];
    const float* fbase = feat + (size_t)l * 4;

    float4 acc = make_float4(0.f, 0.f, 0.f, 0.f);
    float z = 0.f;

    for (int j = 0; j < deg; j += 8) {
        const int rem = deg - j;  // wave-uniform
        const int nb = __builtin_amdgcn_readfirstlane(begin + j);
        // scalar index loads (masked tail -> node 0, weight 0)
        const int s0 = srcs[nb + 0];
        const int s1 = (rem > 1) ? srcs[nb + 1] : 0;
        const int s2 = (rem > 2) ? srcs[nb + 2] : 0;
        const int s3 = (rem > 3) ? srcs[nb + 3] : 0;
        const int s4 = (rem > 4) ? srcs[nb + 4] : 0;
        const int s5 = (rem > 5) ? srcs[nb + 5] : 0;
        const int s6 = (rem > 6) ? srcs[nb + 6] : 0;
        const int s7 = (rem > 7) ? srcs[nb + 7] : 0;
        // scalar el-row loads (uniform float4 -> SGPRs)
        const float4 q0 = *reinterpret_cast<const float4*>(&el[(size_t)s0 * 4]);
        const float4 q1 = *reinterpret_cast<const float4*>(&el[(size_t)s1 * 4]);
        const float4 q2 = *reinterpret_cast<const float4*>(&el[(size_t)s2 * 4]);
        const float4 q3 = *reinterpret_cast<const float4*>(&el[(size_t)s3 * 4]);
        const float4 q4 = *reinterpret_cast<const float4*>(&el[(size_t)s4 * 4]);
        const float4 q5 = *reinterpret_cast<const float4*>(&el[(size_t)s5 * 4]);
        const float4 q6 = *reinterpret_cast<const float4*>(&el[(size_t)s6 * 4]);
        const float4 q7 = *reinterpret_cast<const float4*>(&el[(size_t)s7 * 4]);
        // 8 independent feat-row loads (SGPR base + constant lane voffset)
        const float4 f0 = *reinterpret_cast<const float4*>(fbase + (size_t)s0 * 256);
        const float4 f1 = *reinterpret_cast<const float4*>(fbase + (size_t)s1 * 256);
        const float4 f2 = *reinterpret_cast<const float4*>(fbase + (size_t)s2 * 256);
        const float4 f3 = *reinterpret_cast<const float4*>(fbase + (size_t)s3 * 256);
        const float4 f4 = *reinterpret_cast<const float4*>(fbase + (size_t)s4 * 256);
        const float4 f5 = *reinterpret_cast<const float4*>(fbase + (size_t)s5 * 256);
        const float4 f6 = *reinterpret_cast<const float4*>(fbase + (size_t)s6 * 256);
        const float4 f7 = *reinterpret_cast<const float4*>(fbase + (size_t)s7 * 256);

        float t0 = sel_head(q0, h) + erh; t0 = t0 > 0.f ? t0 : 0.2f * t0;
        float t1 = sel_head(q1, h) + erh; t1 = t1 > 0.f ? t1 : 0.2f * t1;
        float t2 = sel_head(q2, h) + erh; t2 = t2 > 0.f ? t2 : 0.2f * t2;
        float t3 = sel_head(q3, h) + erh; t3 = t3 > 0.f ? t3 : 0.2f * t3;
        float t4 = sel_head(q4, h) + erh; t4 = t4 > 0.f ? t4 : 0.2f * t4;
        float t5 = sel_head(q5, h) + erh; t5 = t5 > 0.f ? t5 : 0.2f * t5;
        float t6 = sel_head(q6, h) + erh; t6 = t6 > 0.f ? t6 : 0.2f * t6;
        float t7 = sel_head(q7, h) + erh; t7 = t7 > 0.f ? t7 : 0.2f * t7;
        const float e0 = __expf(t0);
        const float e1 = (rem > 1) ? __expf(t1) : 0.f;
        const float e2 = (rem > 2) ? __expf(t2) : 0.f;
        const float e3 = (rem > 3) ? __expf(t3) : 0.f;
        const float e4 = (rem > 4) ? __expf(t4) : 0.f;
        const float e5 = (rem > 5) ? __expf(t5) : 0.f;
        const float e6 = (rem > 6) ? __expf(t6) : 0.f;
        const float e7 = (rem > 7) ? __expf(t7) : 0.f;
        z += ((e0 + e1) + (e2 + e3)) + ((e4 + e5) + (e6 + e7));
        acc.x = fmaf(e0, f0.x, acc.x); acc.y = fmaf(e0, f0.y, acc.y);
        acc.z = fmaf(e0, f0.z, acc.z); acc.w = fmaf(e0, f0.w, acc.w);
        acc.x = fmaf(e1, f1.x, acc.x); acc.y = fmaf(e1, f1.y, acc.y);
        acc.z = fmaf(e1, f1.z, acc.z); acc.w = fmaf(e1, f1.w, acc.w);
        acc.x = fmaf(e2, f2.x, acc.x); acc.y = fmaf(e2, f2.y, acc.y);
        acc.z = fmaf(e2, f2.z, acc.z); acc.w = fmaf(e2, f2.w, acc.w);
        acc.x = fmaf(e3, f3.x, acc.x); acc.y = fmaf(e3, f3.y, acc.y);
        acc.z = fmaf(e3, f3.z, acc.z); acc.w = fmaf(e3, f3.w, acc.w);
        acc.x = fmaf(e4, f4.x, acc.x); acc.y = fmaf(e4, f4.y, acc.y);
        acc.z = fmaf(e4, f4.z, acc.z); acc.w = fmaf(e4, f4.w, acc.w);
        acc.x = fmaf(e5, f5.x, acc.x); acc.y = fmaf(e5, f5.y, acc.y);
        acc.z = fmaf(e5, f5.z, acc.z); acc.w = fmaf(e5, f5.w, acc.w);
        acc.x = fmaf(e6, f6.x, acc.x); acc.y = fmaf(e6, f6.y, acc.y);
        acc.z = fmaf(e6, f6.z, acc.z); acc.w = fmaf(e6, f6.w, acc.w);
        acc.x = fmaf(e7, f7.x, acc.x); acc.y = fmaf(e7, f7.y, acc.y);
        acc.z = fmaf(e7, f7.z, acc.z); acc.w = fmaf(e7, f7.w, acc.w);
    }

    const float rz = (z > 0.f) ? __builtin_amdgcn_rcpf(z) : 0.f;
    const float4 bv = *reinterpret_cast<const float4*>(&bias[l * 4]);
    float4 v;
    v.x = fmaf(acc.x, rz, bv.x);
    v.y = fmaf(acc.y, rz, bv.y);
    v.z = fmaf(acc.z, rz, bv.z);
    v.w = fmaf(acc.w, rz, bv.w);
    v.x = v.x > 0.f ? v.x : expm1f(v.x);
    v.y = v.y > 0.f ? v.y : expm1f(v.y);
    v.z = v.z > 0.f ? v.z : expm1f(v.z);
    v.w = v.w > 0.f ? v.w : expm1f(v.w);

    if (!FINAL) {
        *reinterpret_cast<float4*>(&out[(size_t)n * 256 + l * 4]) = v;
    } else {
        // mean over heads: sum lanes l, l+16, l+32, l+48 then /4
        v.x += __shfl_down(v.x, 32, 64); v.y += __shfl_down(v.y, 32, 64);
        v.z += __shfl_down(v.z, 32, 64); v.w += __shfl_down(v.w, 32, 64);
        v.x += __shfl_down(v.x, 16, 64); v.y += __shfl_down(v.y, 16, 64);
        v.z += __shfl_down(v.z, 16, 64); v.w += __shfl_down(v.w, 16, 64);
        if (l < 16) {
            float4 o;
            o.x = 0.25f * v.x; o.y = 0.25f * v.y; o.z = 0.25f * v.z; o.w = 0.25f * v.w;
            *reinterpret_cast<float4*>(&out[(size_t)n * 64 + l * 4]) = o;
        }
    }
}

// ---------------------------------------------------------------------------
extern "C" void kernel_launch(void* const* d_in, const int* in_sizes, int n_in,
                              void* d_out, int out_size, void* d_ws, size_t ws_size,
                              hipStream_t stream) {
    const float* x_feat = (const float*)d_in[0];
    const float* W_fc   = (const float*)d_in[1];
    const float* W1     = (const float*)d_in[2];
    const float* al1    = (const float*)d_in[3];
    const float* ar1    = (const float*)d_in[4];
    const float* b1     = (const float*)d_in[5];
    const float* W2     = (const float*)d_in[6];
    const float* al2    = (const float*)d_in[7];
    const float* ar2    = (const float*)d_in[8];
    const float* b2     = (const float*)d_in[9];
    const int*   src    = (const int*)d_in[10];
    const int*   dst    = (const int*)d_in[11];
    float* out = (float*)d_out;

    const int N = in_sizes[0] / 128;   // 50000
    const int E = in_sizes[10];        // 800000

    char* ws = (char*)d_ws;
    size_t off = 0;
    auto alloc = [&](size_t bytes) -> void* {
        off = (off + 255) & ~(size_t)255;
        void* p = ws + off;
        off += bytes;
        return p;
    };
    float* buf0 = (float*)alloc((size_t)N * 256 * 4);  // h, later g1
    float* buf1 = (float*)alloc((size_t)N * 256 * 4);  // feat1, later feat2
    float* el   = (float*)alloc((size_t)N * 4 * 4);
    float* er   = (float*)alloc((size_t)N * 4 * 4);
    int* deg    = (int*)alloc((size_t)N * 4);
    int* offs   = (int*)alloc((size_t)(N + 1) * 4);
    int* cursor = (int*)alloc((size_t)N * 4);
    int* srcs_sorted = (int*)alloc((size_t)E * 4);
    short* Bfc_h = (short*)alloc((size_t)256 * 128 * 2);
    short* Bfc_l = (short*)alloc((size_t)256 * 128 * 2);
    short* B1_h  = (short*)alloc((size_t)256 * 256 * 2);
    short* B1_l  = (short*)alloc((size_t)256 * 256 * 2);
    short* B2_h  = (short*)alloc((size_t)256 * 256 * 2);
    short* B2_l  = (short*)alloc((size_t)256 * 256 * 2);

    const int eb = (E + 255) / 256;
    dim3 ggrid((N + 127) / 128, 2);
    const int agrid = (N + 3) / 4;

    // CSR build (by dst)
    hipMemsetAsync(deg, 0, (size_t)N * 4, stream);
    count_deg_kernel<<<eb, 256, 0, stream>>>(dst, deg, E);
    scan_kernel<<<1, 1024, 0, stream>>>(deg, offs, cursor, N);
    fill_csr_kernel<<<eb, 256, 0, stream>>>(src, dst, cursor, srcs_sorted, E);

    // weight splits
    wsplit_kernel<<<(128 * 256 + 255) / 256, 256, 0, stream>>>(W_fc, Bfc_h, Bfc_l, 128, 256);
    wsplit_kernel<<<(256 * 256 + 255) / 256, 256, 0, stream>>>(W1, B1_h, B1_l, 256, 256);
    wsplit_kernel<<<(256 * 256 + 255) / 256, 256, 0, stream>>>(W2, B2_h, B2_l, 256, 256);

    // h = tanh(x @ W_fc)
    mfma_gemm_kernel<true, false><<<ggrid, 256, 0, stream>>>(
        x_feat, Bfc_h, Bfc_l, buf0, N, 128, nullptr, nullptr, nullptr, nullptr);
    // feat1 = h @ W1 (+ el/er)
    mfma_gemm_kernel<false, true><<<ggrid, 256, 0, stream>>>(
        buf0, B1_h, B1_l, buf1, N, 256, al1, ar1, el, er);
    // g1 -> buf0
    gat_agg_kernel<false><<<agrid, 256, 0, stream>>>(buf1, el, er, srcs_sorted, offs, b1, buf0, N);
    // feat2 = g1 @ W2 (+ el/er)
    mfma_gemm_kernel<false, true><<<ggrid, 256, 0, stream>>>(
        buf0, B2_h, B2_l, buf1, N, 256, al2, ar2, el, er);
    // final aggregation + head mean -> out
    gat_agg_kernel<true><<<agrid, 256, 0, stream>>>(buf1, el, er, srcs_sorted, offs, b2, out, N);
}